// Round 1
// baseline (1208.115 us; speedup 1.0000x reference)
//
#include <hip/hip_runtime.h>
#include <stdint.h>

typedef unsigned int u32;
typedef unsigned long long u64;

#define N_ANCH 100800
#define NCLS 80
#define ROWF 117
#define KSEL 4096
#define MAXDET 300
#define CONF_T 0.25f
#define IOU_T 0.45f

// workspace layout (bytes)
#define HIST1_OFF 0          // u32[2048]
#define HIST2_OFF 8192       // u32[2048]
#define HIST3_OFF 16384      // u32[1024]
#define CTL_OFF   20480      // u32[64]: 0:b1 1:A1 2:b2 3:A2 4:T 5:Cgt 6:cnt_gt 7:cnt_eq 8:kept 10:V
#define ZERO_BYTES 20736
#define SCORE_OFF 20736      // float[N]
#define BUFA_OFF  424960     // u64[4096]
#define BUFEQ_OFF 458752     // u32[8192]
#define SIDX_OFF  491520     // u32[4096]
#define SSC_OFF   507904     // float[4096]
#define BOXES_OFF 524288     // float4[4096]
#define KEPT_OFF  589824     // u32[304]
#define MAT_OFF   591872     // u64[4096*64]
#define WS_NEEDED (MAT_OFF + (size_t)KSEL * 64 * 8)

__device__ __forceinline__ float fsub_rn_(float a, float b) { return __fadd_rn(a, -b); }

// ---- K1: per-row score (wave per row) + 11-bit histogram ----
__global__ void __launch_bounds__(256) k_score(const float* __restrict__ pred,
                                               float* __restrict__ score,
                                               u32* __restrict__ hist1) {
  int wave = threadIdx.x >> 6, lane = threadIdx.x & 63;
  int row = blockIdx.x * 4 + wave;
  if (row >= N_ANCH) return;
  const float* base = pred + (size_t)row * ROWF;
  float obj = base[4];
  float m = __fmul_rn(base[5 + lane], obj);
  if (lane < 16) m = fmaxf(m, __fmul_rn(base[69 + lane], obj));
#pragma unroll
  for (int off = 32; off >= 1; off >>= 1) m = fmaxf(m, __shfl_xor(m, off));
  float sc = (obj > CONF_T) ? m : 0.0f;
  if (lane == 0) {
    score[row] = sc;
    atomicAdd(&hist1[__float_as_uint(sc) >> 21], 1u);
  }
}

// ---- histogram refine passes ----
__global__ void __launch_bounds__(256) k_hist(const float* __restrict__ score,
                                              const u32* __restrict__ ctl,
                                              u32* __restrict__ hist, int pass) {
  int i = blockIdx.x * 256 + threadIdx.x;
  if (i >= N_ANCH) return;
  u32 key = __float_as_uint(score[i]);
  if (pass == 1) {
    if ((key >> 21) == ctl[0]) atomicAdd(&hist[(key >> 10) & 2047u], 1u);
  } else {
    if ((key >> 10) == ((ctl[0] << 11) | ctl[2])) atomicAdd(&hist[key & 1023u], 1u);
  }
}

// ---- radix-select scan: find bucket containing the K-th largest ----
__global__ void __launch_bounds__(256) k_scan(const u32* __restrict__ hist,
                                              u32* __restrict__ ctl, int nb, int pass) {
  __shared__ u32 partials[256];
  __shared__ u32 prefixs[256];
  int t = threadIdx.x;
  u32 prevA = 0;
  if (pass == 1) prevA = ctl[1];
  else if (pass == 2) prevA = ctl[3];
  int per = nb >> 8;
  int hi = nb - per * t - 1;  // chunk t covers buckets [hi-per+1 .. hi], t=0 is highest
  u32 s = 0;
  for (int q = 0; q < per; ++q) s += hist[hi - q];
  partials[t] = s;
  __syncthreads();
  if (t == 0) {
    u32 c = prevA;
    for (int q = 0; q < 256; ++q) { prefixs[q] = c; c += partials[q]; }
  }
  __syncthreads();
  u32 cum = prefixs[t];
  for (int q = 0; q < per; ++q) {
    u32 h = hist[hi - q];
    if (cum < (u32)KSEL && cum + h >= (u32)KSEL) {
      u32 b = (u32)(hi - q);
      if (pass == 0) { ctl[0] = b; ctl[1] = cum; }
      else if (pass == 1) { ctl[2] = b; ctl[3] = cum; }
      else { ctl[4] = (ctl[0] << 21) | (ctl[2] << 10) | b; ctl[5] = cum; }
      break;
    }
    cum += h;
  }
}

// ---- collect keys > T, and == T separately (tie-break by index) ----
__global__ void __launch_bounds__(256) k_collect(const float* __restrict__ score,
                                                 u32* __restrict__ ctl,
                                                 u64* __restrict__ bufA,
                                                 u32* __restrict__ bufEq) {
  int i = blockIdx.x * 256 + threadIdx.x;
  if (i >= N_ANCH) return;
  u32 key = __float_as_uint(score[i]);
  u32 T = ctl[4];
  if (key > T) {
    u32 pos = atomicAdd(&ctl[6], 1u);
    bufA[pos] = ((u64)key << 32) | (u32)(~(u32)i);
  } else if (key == T) {
    u32 pos = atomicAdd(&ctl[7], 1u);
    if (pos < 8192u) bufEq[pos] = (u32)i;
  }
}

// ---- sort ==T indices ascending, fill remaining slots ----
__global__ void __launch_bounds__(256) k_eqfill(u32* __restrict__ ctl,
                                                const u32* __restrict__ bufEq,
                                                u64* __restrict__ bufA) {
  __shared__ u32 e[8192];
  int t = threadIdx.x;
  u32 cgt = ctl[6];
  u32 need = (u32)KSEL - cgt;
  u32 cnt = ctl[7]; if (cnt > 8192u) cnt = 8192u;
  u32 nsort = 1; while (nsort < cnt) nsort <<= 1;
  for (u32 idx = t; idx < nsort; idx += 256) e[idx] = (idx < cnt) ? bufEq[idx] : 0xFFFFFFFFu;
  __syncthreads();
  for (u32 k = 2; k <= nsort; k <<= 1)
    for (u32 j = k >> 1; j > 0; j >>= 1) {
      for (u32 idx = t; idx < nsort; idx += 256) {
        u32 l = idx ^ j;
        if (l > idx) {
          bool up = ((idx & k) == 0);
          u32 a = e[idx], b = e[l];
          if (up ? (a > b) : (a < b)) { e[idx] = b; e[l] = a; }
        }
      }
      __syncthreads();
    }
  u32 T = ctl[4];
  if (need > cnt) need = cnt;  // unreachable in practice
  for (u32 idx = t; idx < need; idx += 256)
    bufA[cgt + idx] = ((u64)T << 32) | (u32)(~e[idx]);
}

// ---- full sort of 4096 keys desc (score desc, idx asc) + box compute ----
__global__ void __launch_bounds__(1024) k_sort(const u64* __restrict__ bufA,
                                               const float* __restrict__ pred,
                                               u32* __restrict__ sIdx,
                                               float* __restrict__ sScore,
                                               float4* __restrict__ boxes,
                                               u32* __restrict__ ctl) {
  __shared__ u64 a[KSEL];
  int t = threadIdx.x;
  for (int idx = t; idx < KSEL; idx += 1024) a[idx] = bufA[idx];
  __syncthreads();
  for (int k = 2; k <= KSEL; k <<= 1)
    for (int j = k >> 1; j > 0; j >>= 1) {
      for (int idx = t; idx < KSEL; idx += 1024) {
        int l = idx ^ j;
        if (l > idx) {
          bool up = ((idx & k) == 0);
          u64 x = a[idx], y = a[l];
          if (up ? (x < y) : (x > y)) { a[idx] = y; a[l] = x; }  // descending
        }
      }
      __syncthreads();
    }
  for (int idx = t; idx < KSEL; idx += 1024) {
    u64 kv = a[idx];
    u32 oi = ~((u32)kv);
    float sc = __uint_as_float((u32)(kv >> 32));
    sIdx[idx] = oi;
    sScore[idx] = sc;
    if (sc > 0.0f) {
      bool last = (idx == KSEL - 1);
      float nsc = last ? -1.0f : __uint_as_float((u32)(a[idx + 1] >> 32));
      if (last || nsc <= 0.0f) ctl[10] = (u32)(idx + 1);  // valid count V
    }
    const float* row = pred + (size_t)oi * ROWF;
    float x = row[0], y = row[1], w = row[2], h = row[3];
    float hw = __fmul_rn(w, 0.5f), hh = __fmul_rn(h, 0.5f);
    float4 b;
    b.x = fsub_rn_(y, hh);   // y1
    b.y = fsub_rn_(x, hw);   // x1
    b.z = __fadd_rn(y, hh);  // y2
    b.w = __fadd_rn(x, hw);  // x2
    boxes[idx] = b;
  }
}

// ---- IoU suppression bit-matrix: wave = 64 columns, ballot = one word ----
__global__ void __launch_bounds__(256) k_iou(const float4* __restrict__ boxes,
                                             u64* __restrict__ mat) {
  int wave = threadIdx.x >> 6, lane = threadIdx.x & 63;
  int cw = blockIdx.x * 4 + wave;     // word (column-block) index 0..63
  int j = (cw << 6) | lane;           // column 0..4095
  int i0 = blockIdx.y * 128;
  float4 bj = boxes[j];
  float areaJ = __fmul_rn(fsub_rn_(bj.z, bj.x), fsub_rn_(bj.w, bj.y));
  for (int i = i0; i < i0 + 128; ++i) {
    float4 bi = boxes[i];
    float areaI = __fmul_rn(fsub_rn_(bi.z, bi.x), fsub_rn_(bi.w, bi.y));
    float iy1 = fmaxf(bi.x, bj.x);
    float ix1 = fmaxf(bi.y, bj.y);
    float iy2 = fminf(bi.z, bj.z);
    float ix2 = fminf(bi.w, bj.w);
    float dy = fmaxf(fsub_rn_(iy2, iy1), 0.0f);
    float dx = fmaxf(fsub_rn_(ix2, ix1), 0.0f);
    float inter = __fmul_rn(dy, dx);
    float uni = fsub_rn_(__fadd_rn(areaI, areaJ), inter);
    float iou = inter / fmaxf(uni, 1e-9f);
    bool p = (j > i) && (iou > IOU_T);
    u64 m = __ballot(p);
    if (lane == 0) mat[(size_t)i * 64 + cw] = m;
  }
}

// ---- greedy NMS scan: 1 wave, lane owns one 64-bit suppressed word.
// Early exit at MAXDET kept (only first 300 kept matter for the output). ----
__global__ void __launch_bounds__(64) k_nms(const u64* __restrict__ mat,
                                            u32* __restrict__ ctl,
                                            u32* __restrict__ kept) {
  int lane = threadIdx.x;
  int V = (int)ctl[10];
  u64 removed = 0ull;
  u64 rbuf[8], dbuf[8];
#pragma unroll
  for (int d = 0; d < 8; ++d) {
    rbuf[d] = (d < V) ? mat[(size_t)d * 64 + lane] : 0ull;
    dbuf[d] = (d < V) ? mat[(size_t)d * 64 + 0] : 0ull;
  }
  u64 rw = 0ull;
  int kc = 0;
  bool done = false;
  for (int i0 = 0; i0 < V; i0 += 8) {
    if (done) break;
#pragma unroll
    for (int d = 0; d < 8; ++d) {
      int i = i0 + d;
      if (!done && i < V) {
        if ((i & 63) == 0) rw = __shfl(removed, i >> 6);
        bool kp = ((rw >> (i & 63)) & 1ull) == 0ull;
        u64 rowv = rbuf[d];
        u64 dv = dbuf[d];
        int nr = i + 8;
        if (nr < V) {
          rbuf[d] = mat[(size_t)nr * 64 + lane];
          dbuf[d] = mat[(size_t)nr * 64 + (nr >> 6)];
        }
        if (kp) {
          if (lane == 0) kept[kc] = (u32)i;
          removed |= rowv;
          rw |= dv;
          ++kc;
          if (kc == MAXDET) done = true;
        }
      }
    }
  }
  if (lane == 0) ctl[8] = (u32)kc;
}

// ---- output: wave per detection slot ----
__global__ void __launch_bounds__(256) k_out(const float* __restrict__ pred,
                                             const u32* __restrict__ ctl,
                                             const u32* __restrict__ kept,
                                             const u32* __restrict__ sIdx,
                                             const float* __restrict__ sScore,
                                             const float4* __restrict__ boxes,
                                             float* __restrict__ out) {
  int wave = threadIdx.x >> 6, lane = threadIdx.x & 63;
  int s = blockIdx.x * 4 + wave;
  if (s >= MAXDET) return;
  int kc = (int)ctl[8];
  if (s < kc) {
    int pos = (int)kept[s];
    u32 oi = sIdx[pos];
    const float* row = pred + (size_t)oi * ROWF;
    float obj = row[4];
    float v = __fmul_rn(row[5 + lane], obj);
    int ci = lane;
    if (lane < 16) {
      float v2 = __fmul_rn(row[69 + lane], obj);
      if (v2 > v) { v = v2; ci = 64 + lane; }
    }
#pragma unroll
    for (int off = 32; off >= 1; off >>= 1) {
      float ov = __shfl_xor(v, off);
      int oc = __shfl_xor(ci, off);
      if (ov > v || (ov == v && oc < ci)) { v = ov; ci = oc; }
    }
    if (lane == 0) {
      ((float4*)out)[s] = boxes[pos];
      out[1200 + s] = (float)ci;
      out[1500 + s] = sScore[pos];
    }
    if (lane < 32) out[1800 + s * 32 + lane] = row[85 + lane];
  } else {
    if (lane == 0) {
      float4 z = {0.f, 0.f, 0.f, 0.f};
      ((float4*)out)[s] = z;
      out[1200 + s] = 0.f;
      out[1500 + s] = 0.f;
    }
    if (lane < 32) out[1800 + s * 32 + lane] = 0.f;
  }
}

extern "C" void kernel_launch(void* const* d_in, const int* in_sizes, int n_in,
                              void* d_out, int out_size, void* d_ws, size_t ws_size,
                              hipStream_t stream) {
  (void)in_sizes; (void)n_in; (void)out_size;
  if (ws_size < WS_NEEDED) return;  // workspace too small — fail visibly
  const float* pred = (const float*)d_in[0];
  float* out = (float*)d_out;
  char* ws = (char*)d_ws;

  u32* hist1 = (u32*)(ws + HIST1_OFF);
  u32* hist2 = (u32*)(ws + HIST2_OFF);
  u32* hist3 = (u32*)(ws + HIST3_OFF);
  u32* ctl = (u32*)(ws + CTL_OFF);
  float* score = (float*)(ws + SCORE_OFF);
  u64* bufA = (u64*)(ws + BUFA_OFF);
  u32* bufEq = (u32*)(ws + BUFEQ_OFF);
  u32* sIdx = (u32*)(ws + SIDX_OFF);
  float* sScore = (float*)(ws + SSC_OFF);
  float4* boxes = (float4*)(ws + BOXES_OFF);
  u32* kept = (u32*)(ws + KEPT_OFF);
  u64* mat = (u64*)(ws + MAT_OFF);

  hipMemsetAsync(ws, 0, ZERO_BYTES, stream);

  k_score<<<N_ANCH / 4, 256, 0, stream>>>(pred, score, hist1);
  k_scan<<<1, 256, 0, stream>>>(hist1, ctl, 2048, 0);
  int nblk = (N_ANCH + 255) / 256;
  k_hist<<<nblk, 256, 0, stream>>>(score, ctl, hist2, 1);
  k_scan<<<1, 256, 0, stream>>>(hist2, ctl, 2048, 1);
  k_hist<<<nblk, 256, 0, stream>>>(score, ctl, hist3, 2);
  k_scan<<<1, 256, 0, stream>>>(hist3, ctl, 1024, 2);
  k_collect<<<nblk, 256, 0, stream>>>(score, ctl, bufA, bufEq);
  k_eqfill<<<1, 256, 0, stream>>>(ctl, bufEq, bufA);
  k_sort<<<1, 1024, 0, stream>>>(bufA, pred, sIdx, sScore, boxes, ctl);
  k_iou<<<dim3(16, 32), 256, 0, stream>>>(boxes, mat);
  k_nms<<<1, 64, 0, stream>>>(mat, ctl, kept);
  k_out<<<(MAXDET + 3) / 4, 256, 0, stream>>>(pred, ctl, kept, sIdx, sScore, boxes, out);
}

// Round 2
// 377.172 us; speedup vs baseline: 3.2031x; 3.2031x over previous
//
#include <hip/hip_runtime.h>
#include <stdint.h>

typedef unsigned int u32;
typedef unsigned long long u64;

#define N_ANCH 100800
#define NCLS 80
#define ROWF 117
#define KSEL 4096
#define MAXDET 300
#define CONF_T 0.25f
#define IOU_T 0.45f

// workspace layout (bytes)
#define HIST1_OFF 0          // u32[2048]
#define HIST2_OFF 8192       // u32[2048]
#define HIST3_OFF 16384      // u32[1024]
#define CTL_OFF   20480      // u32[64]: 0:b1 1:A1 2:b2 3:A2 4:T 5:Cgt 6:cnt_gt 7:cnt_eq 8:kept 10:V
#define ZERO_BYTES 20736
#define SCORE_OFF 20736      // float[N]
#define BUFA_OFF  424960     // u64[4096]
#define BUFEQ_OFF 458752     // u32[8192]
#define SIDX_OFF  491520     // u32[4096]
#define SSC_OFF   507904     // float[4096]
#define BOXES_OFF 524288     // float4[4096]
#define KEPT_OFF  589824     // u32[304]
#define MAT_OFF   591872     // u64[4096*64]
#define WS_NEEDED (MAT_OFF + (size_t)KSEL * 64 * 8)

__device__ __forceinline__ float fsub_rn_(float a, float b) { return __fadd_rn(a, -b); }

// ---- K1: per-row score (wave per row, 16 rows/wave) + LDS-privatized histogram ----
__global__ void __launch_bounds__(256) k_score(const float* __restrict__ pred,
                                               float* __restrict__ score,
                                               u32* __restrict__ hist1) {
  __shared__ u32 lh[2048];
  int t = threadIdx.x;
  for (int q = t; q < 2048; q += 256) lh[q] = 0u;
  __syncthreads();
  int wave = t >> 6, lane = t & 63;
  int row0 = blockIdx.x * 64 + wave * 16;
#pragma unroll 4
  for (int r = 0; r < 16; ++r) {
    int row = row0 + r;
    const float* base = pred + (size_t)row * ROWF;
    float obj = base[4];
    float m = __fmul_rn(base[5 + lane], obj);
    if (lane < 16) m = fmaxf(m, __fmul_rn(base[69 + lane], obj));
#pragma unroll
    for (int off = 32; off >= 1; off >>= 1) m = fmaxf(m, __shfl_xor(m, off));
    float sc = (obj > CONF_T) ? m : 0.0f;
    if (lane == 0) {
      score[row] = sc;
      atomicAdd(&lh[__float_as_uint(sc) >> 21], 1u);
    }
  }
  __syncthreads();
  for (int q = t; q < 2048; q += 256) {
    u32 c = lh[q];
    if (c) atomicAdd(&hist1[q], c);
  }
}

// ---- histogram refine passes ----
__global__ void __launch_bounds__(256) k_hist(const float* __restrict__ score,
                                              const u32* __restrict__ ctl,
                                              u32* __restrict__ hist, int pass) {
  int i = blockIdx.x * 256 + threadIdx.x;
  if (i >= N_ANCH) return;
  u32 key = __float_as_uint(score[i]);
  if (pass == 1) {
    if ((key >> 21) == ctl[0]) atomicAdd(&hist[(key >> 10) & 2047u], 1u);
  } else {
    if ((key >> 10) == ((ctl[0] << 11) | ctl[2])) atomicAdd(&hist[key & 1023u], 1u);
  }
}

// ---- radix-select scan: find bucket containing the K-th largest ----
__global__ void __launch_bounds__(256) k_scan(const u32* __restrict__ hist,
                                              u32* __restrict__ ctl, int nb, int pass) {
  __shared__ u32 partials[256];
  __shared__ u32 prefixs[256];
  int t = threadIdx.x;
  u32 prevA = 0;
  if (pass == 1) prevA = ctl[1];
  else if (pass == 2) prevA = ctl[3];
  int per = nb >> 8;
  int hi = nb - per * t - 1;  // chunk t covers buckets [hi-per+1 .. hi], t=0 is highest
  u32 s = 0;
  for (int q = 0; q < per; ++q) s += hist[hi - q];
  partials[t] = s;
  __syncthreads();
  if (t == 0) {
    u32 c = prevA;
    for (int q = 0; q < 256; ++q) { prefixs[q] = c; c += partials[q]; }
  }
  __syncthreads();
  u32 cum = prefixs[t];
  for (int q = 0; q < per; ++q) {
    u32 h = hist[hi - q];
    if (cum < (u32)KSEL && cum + h >= (u32)KSEL) {
      u32 b = (u32)(hi - q);
      if (pass == 0) { ctl[0] = b; ctl[1] = cum; }
      else if (pass == 1) { ctl[2] = b; ctl[3] = cum; }
      else { ctl[4] = (ctl[0] << 21) | (ctl[2] << 10) | b; ctl[5] = cum; }
      break;
    }
    cum += h;
  }
}

// ---- collect keys > T, and == T separately (wave-aggregated atomics) ----
__global__ void __launch_bounds__(256) k_collect(const float* __restrict__ score,
                                                 u32* __restrict__ ctl,
                                                 u64* __restrict__ bufA,
                                                 u32* __restrict__ bufEq) {
  int i = blockIdx.x * 256 + threadIdx.x;
  int lane = threadIdx.x & 63;
  bool valid = i < N_ANCH;
  u32 key = valid ? __float_as_uint(score[i]) : 0u;
  u32 T = ctl[4];

  bool pg = valid && (key > T);
  u64 bg = __ballot(pg);
  u32 baseg = 0;
  if (lane == 0 && bg) baseg = atomicAdd(&ctl[6], (u32)__popcll(bg));
  baseg = __shfl(baseg, 0);
  if (pg) {
    u32 pos = baseg + (u32)__popcll(bg & ((1ull << lane) - 1ull));
    bufA[pos] = ((u64)key << 32) | (u32)(~(u32)i);
  }

  bool pe = valid && (key == T);
  u64 be = __ballot(pe);
  u32 basee = 0;
  if (lane == 0 && be) basee = atomicAdd(&ctl[7], (u32)__popcll(be));
  basee = __shfl(basee, 0);
  if (pe) {
    u32 pos = basee + (u32)__popcll(be & ((1ull << lane) - 1ull));
    if (pos < 8192u) bufEq[pos] = (u32)i;
  }
}

// ---- sort ==T indices ascending, fill remaining slots ----
__global__ void __launch_bounds__(256) k_eqfill(u32* __restrict__ ctl,
                                                const u32* __restrict__ bufEq,
                                                u64* __restrict__ bufA) {
  __shared__ u32 e[8192];
  int t = threadIdx.x;
  u32 cgt = ctl[6];
  u32 need = (u32)KSEL - cgt;
  u32 cnt = ctl[7]; if (cnt > 8192u) cnt = 8192u;
  u32 nsort = 1; while (nsort < cnt) nsort <<= 1;
  for (u32 idx = t; idx < nsort; idx += 256) e[idx] = (idx < cnt) ? bufEq[idx] : 0xFFFFFFFFu;
  __syncthreads();
  for (u32 k = 2; k <= nsort; k <<= 1)
    for (u32 j = k >> 1; j > 0; j >>= 1) {
      for (u32 idx = t; idx < nsort; idx += 256) {
        u32 l = idx ^ j;
        if (l > idx) {
          bool up = ((idx & k) == 0);
          u32 a = e[idx], b = e[l];
          if (up ? (a > b) : (a < b)) { e[idx] = b; e[l] = a; }
        }
      }
      __syncthreads();
    }
  u32 T = ctl[4];
  if (need > cnt) need = cnt;  // unreachable in practice
  for (u32 idx = t; idx < need; idx += 256)
    bufA[cgt + idx] = ((u64)T << 32) | (u32)(~e[idx]);
}

// ---- full sort of 4096 keys desc (score desc, idx asc) + box compute ----
__global__ void __launch_bounds__(1024) k_sort(const u64* __restrict__ bufA,
                                               const float* __restrict__ pred,
                                               u32* __restrict__ sIdx,
                                               float* __restrict__ sScore,
                                               float4* __restrict__ boxes,
                                               u32* __restrict__ ctl) {
  __shared__ u64 a[KSEL];
  int t = threadIdx.x;
  for (int idx = t; idx < KSEL; idx += 1024) a[idx] = bufA[idx];
  __syncthreads();
  for (int k = 2; k <= KSEL; k <<= 1)
    for (int j = k >> 1; j > 0; j >>= 1) {
      for (int idx = t; idx < KSEL; idx += 1024) {
        int l = idx ^ j;
        if (l > idx) {
          bool up = ((idx & k) == 0);
          u64 x = a[idx], y = a[l];
          if (up ? (x < y) : (x > y)) { a[idx] = y; a[l] = x; }  // descending
        }
      }
      __syncthreads();
    }
  for (int idx = t; idx < KSEL; idx += 1024) {
    u64 kv = a[idx];
    u32 oi = ~((u32)kv);
    float sc = __uint_as_float((u32)(kv >> 32));
    sIdx[idx] = oi;
    sScore[idx] = sc;
    if (sc > 0.0f) {
      bool last = (idx == KSEL - 1);
      float nsc = last ? -1.0f : __uint_as_float((u32)(a[idx + 1] >> 32));
      if (last || nsc <= 0.0f) ctl[10] = (u32)(idx + 1);  // valid count V
    }
    const float* row = pred + (size_t)oi * ROWF;
    float x = row[0], y = row[1], w = row[2], h = row[3];
    float hw = __fmul_rn(w, 0.5f), hh = __fmul_rn(h, 0.5f);
    float4 b;
    b.x = fsub_rn_(y, hh);   // y1
    b.y = fsub_rn_(x, hw);   // x1
    b.z = __fadd_rn(y, hh);  // y2
    b.w = __fadd_rn(x, hw);  // x2
    boxes[idx] = b;
  }
}

// ---- IoU suppression bit-matrix: wave = 64 columns, ballot = one word ----
__global__ void __launch_bounds__(256) k_iou(const float4* __restrict__ boxes,
                                             u64* __restrict__ mat) {
  int wave = threadIdx.x >> 6, lane = threadIdx.x & 63;
  int cw = blockIdx.x * 4 + wave;     // word (column-block) index 0..63
  int j = (cw << 6) | lane;           // column 0..4095
  int i0 = blockIdx.y * 128;
  float4 bj = boxes[j];
  float areaJ = __fmul_rn(fsub_rn_(bj.z, bj.x), fsub_rn_(bj.w, bj.y));
  for (int i = i0; i < i0 + 128; ++i) {
    float4 bi = boxes[i];
    float areaI = __fmul_rn(fsub_rn_(bi.z, bi.x), fsub_rn_(bi.w, bi.y));
    float iy1 = fmaxf(bi.x, bj.x);
    float ix1 = fmaxf(bi.y, bj.y);
    float iy2 = fminf(bi.z, bj.z);
    float ix2 = fminf(bi.w, bj.w);
    float dy = fmaxf(fsub_rn_(iy2, iy1), 0.0f);
    float dx = fmaxf(fsub_rn_(ix2, ix1), 0.0f);
    float inter = __fmul_rn(dy, dx);
    float uni = fsub_rn_(__fadd_rn(areaI, areaJ), inter);
    float iou = inter / fmaxf(uni, 1e-9f);
    bool p = (j > i) && (iou > IOU_T);
    u64 m = __ballot(p);
    if (lane == 0) mat[(size_t)i * 64 + cw] = m;
  }
}

// ---- greedy NMS scan: 1 wave, lane owns one 64-bit suppressed word.
// Early exit at MAXDET kept (only first 300 kept matter for the output). ----
__global__ void __launch_bounds__(64) k_nms(const u64* __restrict__ mat,
                                            u32* __restrict__ ctl,
                                            u32* __restrict__ kept) {
  int lane = threadIdx.x;
  int V = (int)ctl[10];
  u64 removed = 0ull;
  u64 rbuf[8], dbuf[8];
#pragma unroll
  for (int d = 0; d < 8; ++d) {
    rbuf[d] = (d < V) ? mat[(size_t)d * 64 + lane] : 0ull;
    dbuf[d] = (d < V) ? mat[(size_t)d * 64 + 0] : 0ull;
  }
  u64 rw = 0ull;
  int kc = 0;
  bool done = false;
  for (int i0 = 0; i0 < V; i0 += 8) {
    if (done) break;
#pragma unroll
    for (int d = 0; d < 8; ++d) {
      int i = i0 + d;
      if (!done && i < V) {
        if ((i & 63) == 0) rw = __shfl(removed, i >> 6);
        bool kp = ((rw >> (i & 63)) & 1ull) == 0ull;
        u64 rowv = rbuf[d];
        u64 dv = dbuf[d];
        int nr = i + 8;
        if (nr < V) {
          rbuf[d] = mat[(size_t)nr * 64 + lane];
          dbuf[d] = mat[(size_t)nr * 64 + (nr >> 6)];
        }
        if (kp) {
          if (lane == 0) kept[kc] = (u32)i;
          removed |= rowv;
          rw |= dv;
          ++kc;
          if (kc == MAXDET) done = true;
        }
      }
    }
  }
  if (lane == 0) ctl[8] = (u32)kc;
}

// ---- output: wave per detection slot ----
__global__ void __launch_bounds__(256) k_out(const float* __restrict__ pred,
                                             const u32* __restrict__ ctl,
                                             const u32* __restrict__ kept,
                                             const u32* __restrict__ sIdx,
                                             const float* __restrict__ sScore,
                                             const float4* __restrict__ boxes,
                                             float* __restrict__ out) {
  int wave = threadIdx.x >> 6, lane = threadIdx.x & 63;
  int s = blockIdx.x * 4 + wave;
  if (s >= MAXDET) return;
  int kc = (int)ctl[8];
  if (s < kc) {
    int pos = (int)kept[s];
    u32 oi = sIdx[pos];
    const float* row = pred + (size_t)oi * ROWF;
    float obj = row[4];
    float v = __fmul_rn(row[5 + lane], obj);
    int ci = lane;
    if (lane < 16) {
      float v2 = __fmul_rn(row[69 + lane], obj);
      if (v2 > v) { v = v2; ci = 64 + lane; }
    }
#pragma unroll
    for (int off = 32; off >= 1; off >>= 1) {
      float ov = __shfl_xor(v, off);
      int oc = __shfl_xor(ci, off);
      if (ov > v || (ov == v && oc < ci)) { v = ov; ci = oc; }
    }
    if (lane == 0) {
      ((float4*)out)[s] = boxes[pos];
      out[1200 + s] = (float)ci;
      out[1500 + s] = sScore[pos];
    }
    if (lane < 32) out[1800 + s * 32 + lane] = row[85 + lane];
  } else {
    if (lane == 0) {
      float4 z = {0.f, 0.f, 0.f, 0.f};
      ((float4*)out)[s] = z;
      out[1200 + s] = 0.f;
      out[1500 + s] = 0.f;
    }
    if (lane < 32) out[1800 + s * 32 + lane] = 0.f;
  }
}

extern "C" void kernel_launch(void* const* d_in, const int* in_sizes, int n_in,
                              void* d_out, int out_size, void* d_ws, size_t ws_size,
                              hipStream_t stream) {
  (void)in_sizes; (void)n_in; (void)out_size;
  if (ws_size < WS_NEEDED) return;  // workspace too small — fail visibly
  const float* pred = (const float*)d_in[0];
  float* out = (float*)d_out;
  char* ws = (char*)d_ws;

  u32* hist1 = (u32*)(ws + HIST1_OFF);
  u32* hist2 = (u32*)(ws + HIST2_OFF);
  u32* hist3 = (u32*)(ws + HIST3_OFF);
  u32* ctl = (u32*)(ws + CTL_OFF);
  float* score = (float*)(ws + SCORE_OFF);
  u64* bufA = (u64*)(ws + BUFA_OFF);
  u32* bufEq = (u32*)(ws + BUFEQ_OFF);
  u32* sIdx = (u32*)(ws + SIDX_OFF);
  float* sScore = (float*)(ws + SSC_OFF);
  float4* boxes = (float4*)(ws + BOXES_OFF);
  u32* kept = (u32*)(ws + KEPT_OFF);
  u64* mat = (u64*)(ws + MAT_OFF);

  hipMemsetAsync(ws, 0, ZERO_BYTES, stream);

  k_score<<<N_ANCH / 64, 256, 0, stream>>>(pred, score, hist1);
  k_scan<<<1, 256, 0, stream>>>(hist1, ctl, 2048, 0);
  int nblk = (N_ANCH + 255) / 256;
  k_hist<<<nblk, 256, 0, stream>>>(score, ctl, hist2, 1);
  k_scan<<<1, 256, 0, stream>>>(hist2, ctl, 2048, 1);
  k_hist<<<nblk, 256, 0, stream>>>(score, ctl, hist3, 2);
  k_scan<<<1, 256, 0, stream>>>(hist3, ctl, 1024, 2);
  k_collect<<<nblk, 256, 0, stream>>>(score, ctl, bufA, bufEq);
  k_eqfill<<<1, 256, 0, stream>>>(ctl, bufEq, bufA);
  k_sort<<<1, 1024, 0, stream>>>(bufA, pred, sIdx, sScore, boxes, ctl);
  k_iou<<<dim3(16, 32), 256, 0, stream>>>(boxes, mat);
  k_nms<<<1, 64, 0, stream>>>(mat, ctl, kept);
  k_out<<<(MAXDET + 3) / 4, 256, 0, stream>>>(pred, ctl, kept, sIdx, sScore, boxes, out);
}

// Round 3
// 282.267 us; speedup vs baseline: 4.2800x; 1.3362x over previous
//
#include <hip/hip_runtime.h>
#include <stdint.h>

typedef unsigned int u32;
typedef unsigned long long u64;

#define N_ANCH 100800
#define NCLS 80
#define ROWF 117
#define KSEL 4096
#define MAXDET 300
#define CONF_T 0.25f
#define IOU_T 0.45f

// workspace layout (bytes)
#define HIST1_OFF 0          // u32[2048]
#define HIST2_OFF 8192       // u32[2048]
#define HIST3_OFF 16384      // u32[1024]
#define CTL_OFF   20480      // u32[64]: 0:b1 1:A1 2:b2 3:A2 4:T 5:Cgt 6:cnt_gt 7:cnt_eq 8:kept 10:V
#define ZERO_BYTES 20736
#define SCORE_OFF 20736      // float[N]
#define BUFA_OFF  424960     // u64[4096]
#define BUFEQ_OFF 458752     // u32[8192]
#define SIDX_OFF  491520     // u32[4096]
#define SSC_OFF   507904     // float[4096]
#define BOXES_OFF 524288     // float4[4096]
#define KEPT_OFF  589824     // u32[304]
#define MAT_OFF   591872     // u64[4096*64]
#define WS_NEEDED (MAT_OFF + (size_t)KSEL * 64 * 8)

__device__ __forceinline__ float fsub_rn_(float a, float b) { return __fadd_rn(a, -b); }

__device__ __forceinline__ u64 readlane64_(u64 v, int l) {
  u32 lo = (u32)__builtin_amdgcn_readlane((int)(u32)v, l);
  u32 hi = (u32)__builtin_amdgcn_readlane((int)(u32)(v >> 32), l);
  return ((u64)hi << 32) | lo;
}

// ---- K1: per-row score (wave per row, 16 rows/wave) + LDS-privatized histogram ----
__global__ void __launch_bounds__(256) k_score(const float* __restrict__ pred,
                                               float* __restrict__ score,
                                               u32* __restrict__ hist1) {
  __shared__ u32 lh[2048];
  int t = threadIdx.x;
  for (int q = t; q < 2048; q += 256) lh[q] = 0u;
  __syncthreads();
  int wave = t >> 6, lane = t & 63;
  int row0 = blockIdx.x * 64 + wave * 16;
#pragma unroll 4
  for (int r = 0; r < 16; ++r) {
    int row = row0 + r;
    const float* base = pred + (size_t)row * ROWF;
    float obj = base[4];
    float m = __fmul_rn(base[5 + lane], obj);
    if (lane < 16) m = fmaxf(m, __fmul_rn(base[69 + lane], obj));
#pragma unroll
    for (int off = 32; off >= 1; off >>= 1) m = fmaxf(m, __shfl_xor(m, off));
    float sc = (obj > CONF_T) ? m : 0.0f;
    if (lane == 0) {
      score[row] = sc;
      atomicAdd(&lh[__float_as_uint(sc) >> 21], 1u);
    }
  }
  __syncthreads();
  for (int q = t; q < 2048; q += 256) {
    u32 c = lh[q];
    if (c) atomicAdd(&hist1[q], c);
  }
}

// ---- histogram refine passes ----
__global__ void __launch_bounds__(256) k_hist(const float* __restrict__ score,
                                              const u32* __restrict__ ctl,
                                              u32* __restrict__ hist, int pass) {
  int i = blockIdx.x * 256 + threadIdx.x;
  if (i >= N_ANCH) return;
  u32 key = __float_as_uint(score[i]);
  if (pass == 1) {
    if ((key >> 21) == ctl[0]) atomicAdd(&hist[(key >> 10) & 2047u], 1u);
  } else {
    if ((key >> 10) == ((ctl[0] << 11) | ctl[2])) atomicAdd(&hist[key & 1023u], 1u);
  }
}

// ---- radix-select scan: find bucket containing the K-th largest ----
__global__ void __launch_bounds__(256) k_scan(const u32* __restrict__ hist,
                                              u32* __restrict__ ctl, int nb, int pass) {
  __shared__ u32 partials[256];
  __shared__ u32 prefixs[256];
  int t = threadIdx.x;
  u32 prevA = 0;
  if (pass == 1) prevA = ctl[1];
  else if (pass == 2) prevA = ctl[3];
  int per = nb >> 8;
  int hi = nb - per * t - 1;  // chunk t covers buckets [hi-per+1 .. hi], t=0 is highest
  u32 s = 0;
  for (int q = 0; q < per; ++q) s += hist[hi - q];
  partials[t] = s;
  __syncthreads();
  if (t == 0) {
    u32 c = prevA;
    for (int q = 0; q < 256; ++q) { prefixs[q] = c; c += partials[q]; }
  }
  __syncthreads();
  u32 cum = prefixs[t];
  for (int q = 0; q < per; ++q) {
    u32 h = hist[hi - q];
    if (cum < (u32)KSEL && cum + h >= (u32)KSEL) {
      u32 b = (u32)(hi - q);
      if (pass == 0) { ctl[0] = b; ctl[1] = cum; }
      else if (pass == 1) { ctl[2] = b; ctl[3] = cum; }
      else { ctl[4] = (ctl[0] << 21) | (ctl[2] << 10) | b; ctl[5] = cum; }
      break;
    }
    cum += h;
  }
}

// ---- collect keys > T, and == T separately (wave-aggregated atomics) ----
__global__ void __launch_bounds__(256) k_collect(const float* __restrict__ score,
                                                 u32* __restrict__ ctl,
                                                 u64* __restrict__ bufA,
                                                 u32* __restrict__ bufEq) {
  int i = blockIdx.x * 256 + threadIdx.x;
  int lane = threadIdx.x & 63;
  bool valid = i < N_ANCH;
  u32 key = valid ? __float_as_uint(score[i]) : 0u;
  u32 T = ctl[4];

  bool pg = valid && (key > T);
  u64 bg = __ballot(pg);
  u32 baseg = 0;
  if (lane == 0 && bg) baseg = atomicAdd(&ctl[6], (u32)__popcll(bg));
  baseg = __shfl(baseg, 0);
  if (pg) {
    u32 pos = baseg + (u32)__popcll(bg & ((1ull << lane) - 1ull));
    bufA[pos] = ((u64)key << 32) | (u32)(~(u32)i);
  }

  bool pe = valid && (key == T);
  u64 be = __ballot(pe);
  u32 basee = 0;
  if (lane == 0 && be) basee = atomicAdd(&ctl[7], (u32)__popcll(be));
  basee = __shfl(basee, 0);
  if (pe) {
    u32 pos = basee + (u32)__popcll(be & ((1ull << lane) - 1ull));
    if (pos < 8192u) bufEq[pos] = (u32)i;
  }
}

// ---- sort ==T indices ascending, fill remaining slots ----
__global__ void __launch_bounds__(256) k_eqfill(u32* __restrict__ ctl,
                                                const u32* __restrict__ bufEq,
                                                u64* __restrict__ bufA) {
  __shared__ u32 e[8192];
  int t = threadIdx.x;
  u32 cgt = ctl[6];
  u32 need = (u32)KSEL - cgt;
  u32 cnt = ctl[7]; if (cnt > 8192u) cnt = 8192u;
  u32 nsort = 1; while (nsort < cnt) nsort <<= 1;
  for (u32 idx = t; idx < nsort; idx += 256) e[idx] = (idx < cnt) ? bufEq[idx] : 0xFFFFFFFFu;
  __syncthreads();
  for (u32 k = 2; k <= nsort; k <<= 1)
    for (u32 j = k >> 1; j > 0; j >>= 1) {
      for (u32 idx = t; idx < nsort; idx += 256) {
        u32 l = idx ^ j;
        if (l > idx) {
          bool up = ((idx & k) == 0);
          u32 a = e[idx], b = e[l];
          if (up ? (a > b) : (a < b)) { e[idx] = b; e[l] = a; }
        }
      }
      __syncthreads();
    }
  u32 T = ctl[4];
  if (need > cnt) need = cnt;  // unreachable in practice
  for (u32 idx = t; idx < need; idx += 256)
    bufA[cgt + idx] = ((u64)T << 32) | (u32)(~e[idx]);
}

// ---- full sort of 4096 keys desc (score desc, idx asc) + box compute ----
__global__ void __launch_bounds__(1024) k_sort(const u64* __restrict__ bufA,
                                               const float* __restrict__ pred,
                                               u32* __restrict__ sIdx,
                                               float* __restrict__ sScore,
                                               float4* __restrict__ boxes,
                                               u32* __restrict__ ctl) {
  __shared__ u64 a[KSEL];
  int t = threadIdx.x;
  for (int idx = t; idx < KSEL; idx += 1024) a[idx] = bufA[idx];
  __syncthreads();
  for (int k = 2; k <= KSEL; k <<= 1)
    for (int j = k >> 1; j > 0; j >>= 1) {
      for (int idx = t; idx < KSEL; idx += 1024) {
        int l = idx ^ j;
        if (l > idx) {
          bool up = ((idx & k) == 0);
          u64 x = a[idx], y = a[l];
          if (up ? (x < y) : (x > y)) { a[idx] = y; a[l] = x; }  // descending
        }
      }
      __syncthreads();
    }
  for (int idx = t; idx < KSEL; idx += 1024) {
    u64 kv = a[idx];
    u32 oi = ~((u32)kv);
    float sc = __uint_as_float((u32)(kv >> 32));
    sIdx[idx] = oi;
    sScore[idx] = sc;
    if (sc > 0.0f) {
      bool last = (idx == KSEL - 1);
      float nsc = last ? -1.0f : __uint_as_float((u32)(a[idx + 1] >> 32));
      if (last || nsc <= 0.0f) ctl[10] = (u32)(idx + 1);  // valid count V
    }
    const float* row = pred + (size_t)oi * ROWF;
    float x = row[0], y = row[1], w = row[2], h = row[3];
    float hw = __fmul_rn(w, 0.5f), hh = __fmul_rn(h, 0.5f);
    float4 b;
    b.x = fsub_rn_(y, hh);   // y1
    b.y = fsub_rn_(x, hw);   // x1
    b.z = __fadd_rn(y, hh);  // y2
    b.w = __fadd_rn(x, hw);  // x2
    boxes[idx] = b;
  }
}

// ---- IoU suppression bit-matrix: wave = 64 columns, ballot = one word ----
__global__ void __launch_bounds__(256) k_iou(const float4* __restrict__ boxes,
                                             u64* __restrict__ mat) {
  int wave = threadIdx.x >> 6, lane = threadIdx.x & 63;
  int cw = blockIdx.x * 4 + wave;     // word (column-block) index 0..63
  int j = (cw << 6) | lane;           // column 0..4095
  int i0 = blockIdx.y * 128;
  float4 bj = boxes[j];
  float areaJ = __fmul_rn(fsub_rn_(bj.z, bj.x), fsub_rn_(bj.w, bj.y));
  for (int i = i0; i < i0 + 128; ++i) {
    float4 bi = boxes[i];
    float areaI = __fmul_rn(fsub_rn_(bi.z, bi.x), fsub_rn_(bi.w, bi.y));
    float iy1 = fmaxf(bi.x, bj.x);
    float ix1 = fmaxf(bi.y, bj.y);
    float iy2 = fminf(bi.z, bj.z);
    float ix2 = fminf(bi.w, bj.w);
    float dy = fmaxf(fsub_rn_(iy2, iy1), 0.0f);
    float dx = fmaxf(fsub_rn_(ix2, ix1), 0.0f);
    float inter = __fmul_rn(dy, dx);
    float uni = fsub_rn_(__fadd_rn(areaI, areaJ), inter);
    float iou = inter / fmaxf(uni, 1e-9f);
    bool p = (j > i) && (iou > IOU_T);
    u64 m = __ballot(p);
    if (lane == 0) mat[(size_t)i * 64 + cw] = m;
  }
}

// ---- greedy NMS scan: 1 wave, lane owns one 64-bit suppressed word.
// 64-deep unconditional register prefetch ring; diagonal word via readlane
// (scalar) instead of a second load stream; early exit at MAXDET kept. ----
#define NMS_D 64
__global__ void __launch_bounds__(64) k_nms(const u64* __restrict__ mat,
                                            u32* __restrict__ ctl,
                                            u32* __restrict__ kept) {
  int lane = threadIdx.x;
  int V = (int)ctl[10];
  u64 rbuf[NMS_D];
#pragma unroll
  for (int d = 0; d < NMS_D; ++d) {
    int pr = (d < V) ? d : 0;
    rbuf[d] = mat[(size_t)pr * 64 + lane];
  }
  u64 removed = 0ull;
  u64 rw = 0ull;
  int kc = 0;
  bool done = (V == 0);
  for (int i0 = 0; i0 < V; i0 += NMS_D) {
    if (done) break;
#pragma unroll
    for (int d = 0; d < NMS_D; ++d) {
      int i = i0 + d;
      u64 rowv = rbuf[d];
      // unconditional prefetch of row i+NMS_D (clamped; dead value past V)
      int nr = i + NMS_D;
      int pr = (nr < V) ? nr : 0;
      rbuf[d] = mat[(size_t)pr * 64 + lane];
      if (!done && i < V) {
        int w = i >> 6;
        if ((i & 63) == 0) rw = readlane64_(removed, w);
        if (((rw >> (i & 63)) & 1ull) == 0ull) {
          if (lane == 0) kept[kc] = (u32)i;
          removed |= rowv;
          rw |= readlane64_(rowv, w);
          ++kc;
          if (kc == MAXDET) done = true;
        }
      }
    }
  }
  if (lane == 0) ctl[8] = (u32)kc;
}

// ---- output: wave per detection slot ----
__global__ void __launch_bounds__(256) k_out(const float* __restrict__ pred,
                                             const u32* __restrict__ ctl,
                                             const u32* __restrict__ kept,
                                             const u32* __restrict__ sIdx,
                                             const float* __restrict__ sScore,
                                             const float4* __restrict__ boxes,
                                             float* __restrict__ out) {
  int wave = threadIdx.x >> 6, lane = threadIdx.x & 63;
  int s = blockIdx.x * 4 + wave;
  if (s >= MAXDET) return;
  int kc = (int)ctl[8];
  if (s < kc) {
    int pos = (int)kept[s];
    u32 oi = sIdx[pos];
    const float* row = pred + (size_t)oi * ROWF;
    float obj = row[4];
    float v = __fmul_rn(row[5 + lane], obj);
    int ci = lane;
    if (lane < 16) {
      float v2 = __fmul_rn(row[69 + lane], obj);
      if (v2 > v) { v = v2; ci = 64 + lane; }
    }
#pragma unroll
    for (int off = 32; off >= 1; off >>= 1) {
      float ov = __shfl_xor(v, off);
      int oc = __shfl_xor(ci, off);
      if (ov > v || (ov == v && oc < ci)) { v = ov; ci = oc; }
    }
    if (lane == 0) {
      ((float4*)out)[s] = boxes[pos];
      out[1200 + s] = (float)ci;
      out[1500 + s] = sScore[pos];
    }
    if (lane < 32) out[1800 + s * 32 + lane] = row[85 + lane];
  } else {
    if (lane == 0) {
      float4 z = {0.f, 0.f, 0.f, 0.f};
      ((float4*)out)[s] = z;
      out[1200 + s] = 0.f;
      out[1500 + s] = 0.f;
    }
    if (lane < 32) out[1800 + s * 32 + lane] = 0.f;
  }
}

extern "C" void kernel_launch(void* const* d_in, const int* in_sizes, int n_in,
                              void* d_out, int out_size, void* d_ws, size_t ws_size,
                              hipStream_t stream) {
  (void)in_sizes; (void)n_in; (void)out_size;
  if (ws_size < WS_NEEDED) return;  // workspace too small — fail visibly
  const float* pred = (const float*)d_in[0];
  float* out = (float*)d_out;
  char* ws = (char*)d_ws;

  u32* hist1 = (u32*)(ws + HIST1_OFF);
  u32* hist2 = (u32*)(ws + HIST2_OFF);
  u32* hist3 = (u32*)(ws + HIST3_OFF);
  u32* ctl = (u32*)(ws + CTL_OFF);
  float* score = (float*)(ws + SCORE_OFF);
  u64* bufA = (u64*)(ws + BUFA_OFF);
  u32* bufEq = (u32*)(ws + BUFEQ_OFF);
  u32* sIdx = (u32*)(ws + SIDX_OFF);
  float* sScore = (float*)(ws + SSC_OFF);
  float4* boxes = (float4*)(ws + BOXES_OFF);
  u32* kept = (u32*)(ws + KEPT_OFF);
  u64* mat = (u64*)(ws + MAT_OFF);

  hipMemsetAsync(ws, 0, ZERO_BYTES, stream);

  k_score<<<N_ANCH / 64, 256, 0, stream>>>(pred, score, hist1);
  k_scan<<<1, 256, 0, stream>>>(hist1, ctl, 2048, 0);
  int nblk = (N_ANCH + 255) / 256;
  k_hist<<<nblk, 256, 0, stream>>>(score, ctl, hist2, 1);
  k_scan<<<1, 256, 0, stream>>>(hist2, ctl, 2048, 1);
  k_hist<<<nblk, 256, 0, stream>>>(score, ctl, hist3, 2);
  k_scan<<<1, 256, 0, stream>>>(hist3, ctl, 1024, 2);
  k_collect<<<nblk, 256, 0, stream>>>(score, ctl, bufA, bufEq);
  k_eqfill<<<1, 256, 0, stream>>>(ctl, bufEq, bufA);
  k_sort<<<1, 1024, 0, stream>>>(bufA, pred, sIdx, sScore, boxes, ctl);
  k_iou<<<dim3(16, 32), 256, 0, stream>>>(boxes, mat);
  k_nms<<<1, 64, 0, stream>>>(mat, ctl, kept);
  k_out<<<(MAXDET + 3) / 4, 256, 0, stream>>>(pred, ctl, kept, sIdx, sScore, boxes, out);
}

// Round 5
// 248.943 us; speedup vs baseline: 4.8530x; 1.1339x over previous
//
#include <hip/hip_runtime.h>
#include <stdint.h>

typedef unsigned int u32;
typedef unsigned long long u64;

#define N_ANCH 100800
#define NCLS 80
#define ROWF 117
#define KSEL 4096
#define MAXDET 300
#define CONF_T 0.25f
#define IOU_T 0.45f

// workspace layout (bytes)
#define HIST1_OFF 0          // u32[2048]
#define HIST2_OFF 8192       // u32[2048]
#define HIST3_OFF 16384      // u32[1024]
#define CTL_OFF   20480      // u32[64]: 0:b1 1:A1 2:b2 3:A2 4:T 5:Cgt 6:cnt_gt 7:cnt_eq 8:kept 10:V
#define ZERO_BYTES 20736
#define SCORE_OFF 20736      // float[N]
#define BUFA_OFF  424960     // u64[4096]
#define BUFEQ_OFF 458752     // u32[8192]
#define SIDX_OFF  491520     // u32[4096]
#define SSC_OFF   507904     // float[4096]
#define BOXES_OFF 524288     // float4[4096]
#define KEPT_OFF  589824     // u32[304]
#define MAT_OFF   591872     // u64[4096*64]
#define WS_NEEDED (MAT_OFF + (size_t)KSEL * 64 * 8)

__device__ __forceinline__ float fsub_rn_(float a, float b) { return __fadd_rn(a, -b); }

__device__ __forceinline__ u64 readlane64_(u64 v, int l) {
  u32 lo = (u32)__builtin_amdgcn_readlane((int)(u32)v, l);
  u32 hi = (u32)__builtin_amdgcn_readlane((int)(u32)(v >> 32), l);
  return ((u64)hi << 32) | lo;
}

__device__ __forceinline__ u64 mx64_(u64 a, u64 b) { return a > b ? a : b; }
__device__ __forceinline__ u64 mn64_(u64 a, u64 b) { return a < b ? a : b; }

// ---- K1: per-row score (wave per row, 16 rows/wave) + LDS-privatized histogram ----
__global__ void __launch_bounds__(256) k_score(const float* __restrict__ pred,
                                               float* __restrict__ score,
                                               u32* __restrict__ hist1) {
  __shared__ u32 lh[2048];
  int t = threadIdx.x;
  for (int q = t; q < 2048; q += 256) lh[q] = 0u;
  __syncthreads();
  int wave = t >> 6, lane = t & 63;
  int row0 = blockIdx.x * 64 + wave * 16;
#pragma unroll 4
  for (int r = 0; r < 16; ++r) {
    int row = row0 + r;
    const float* base = pred + (size_t)row * ROWF;
    float obj = base[4];
    float m = __fmul_rn(base[5 + lane], obj);
    if (lane < 16) m = fmaxf(m, __fmul_rn(base[69 + lane], obj));
#pragma unroll
    for (int off = 32; off >= 1; off >>= 1) m = fmaxf(m, __shfl_xor(m, off));
    float sc = (obj > CONF_T) ? m : 0.0f;
    if (lane == 0) {
      score[row] = sc;
      atomicAdd(&lh[__float_as_uint(sc) >> 21], 1u);
    }
  }
  __syncthreads();
  for (int q = t; q < 2048; q += 256) {
    u32 c = lh[q];
    if (c) atomicAdd(&hist1[q], c);
  }
}

// ---- histogram refine passes ----
__global__ void __launch_bounds__(256) k_hist(const float* __restrict__ score,
                                              const u32* __restrict__ ctl,
                                              u32* __restrict__ hist, int pass) {
  int i = blockIdx.x * 256 + threadIdx.x;
  if (i >= N_ANCH) return;
  u32 key = __float_as_uint(score[i]);
  if (pass == 1) {
    if ((key >> 21) == ctl[0]) atomicAdd(&hist[(key >> 10) & 2047u], 1u);
  } else {
    if ((key >> 10) == ((ctl[0] << 11) | ctl[2])) atomicAdd(&hist[key & 1023u], 1u);
  }
}

// ---- radix-select scan: find bucket containing the K-th largest ----
__global__ void __launch_bounds__(256) k_scan(const u32* __restrict__ hist,
                                              u32* __restrict__ ctl, int nb, int pass) {
  __shared__ u32 partials[256];
  __shared__ u32 prefixs[256];
  int t = threadIdx.x;
  u32 prevA = 0;
  if (pass == 1) prevA = ctl[1];
  else if (pass == 2) prevA = ctl[3];
  int per = nb >> 8;
  int hi = nb - per * t - 1;  // chunk t covers buckets [hi-per+1 .. hi], t=0 is highest
  u32 s = 0;
  for (int q = 0; q < per; ++q) s += hist[hi - q];
  partials[t] = s;
  __syncthreads();
  if (t == 0) {
    u32 c = prevA;
    for (int q = 0; q < 256; ++q) { prefixs[q] = c; c += partials[q]; }
  }
  __syncthreads();
  u32 cum = prefixs[t];
  for (int q = 0; q < per; ++q) {
    u32 h = hist[hi - q];
    if (cum < (u32)KSEL && cum + h >= (u32)KSEL) {
      u32 b = (u32)(hi - q);
      if (pass == 0) { ctl[0] = b; ctl[1] = cum; }
      else if (pass == 1) { ctl[2] = b; ctl[3] = cum; }
      else { ctl[4] = (ctl[0] << 21) | (ctl[2] << 10) | b; ctl[5] = cum; }
      break;
    }
    cum += h;
  }
}

// ---- collect keys > T, and == T separately (wave-aggregated atomics) ----
__global__ void __launch_bounds__(256) k_collect(const float* __restrict__ score,
                                                 u32* __restrict__ ctl,
                                                 u64* __restrict__ bufA,
                                                 u32* __restrict__ bufEq) {
  int i = blockIdx.x * 256 + threadIdx.x;
  int lane = threadIdx.x & 63;
  bool valid = i < N_ANCH;
  u32 key = valid ? __float_as_uint(score[i]) : 0u;
  u32 T = ctl[4];

  bool pg = valid && (key > T);
  u64 bg = __ballot(pg);
  u32 baseg = 0;
  if (lane == 0 && bg) baseg = atomicAdd(&ctl[6], (u32)__popcll(bg));
  baseg = __shfl(baseg, 0);
  if (pg) {
    u32 pos = baseg + (u32)__popcll(bg & ((1ull << lane) - 1ull));
    bufA[pos] = ((u64)key << 32) | (u32)(~(u32)i);
  }

  bool pe = valid && (key == T);
  u64 be = __ballot(pe);
  u32 basee = 0;
  if (lane == 0 && be) basee = atomicAdd(&ctl[7], (u32)__popcll(be));
  basee = __shfl(basee, 0);
  if (pe) {
    u32 pos = basee + (u32)__popcll(be & ((1ull << lane) - 1ull));
    if (pos < 8192u) bufEq[pos] = (u32)i;
  }
}

// ---- fused: tie-fill (former k_eqfill) + register-resident bitonic sort of
// 4096 u64 keys (descending) + epilogue (boxes, V). Wave w owns elements
// [256w,256w+256): slot s, lane l <-> element (w<<8)|(s<<6)|l.
// j<=32: shfl_xor, no barrier. j=64/128: pure-register. j>=256: LDS+2 barriers. ----
__global__ void __launch_bounds__(1024) k_sort(const u64* __restrict__ bufA,
                                               const u32* __restrict__ bufEq,
                                               const float* __restrict__ pred,
                                               u32* __restrict__ sIdx,
                                               float* __restrict__ sScore,
                                               float4* __restrict__ boxes,
                                               u32* __restrict__ ctl) {
  __shared__ u64 a[KSEL];
  u32* a32 = (u32*)a;
  int t = threadIdx.x;
  int w = t >> 6, l = t & 63;

  u32 cgt = ctl[6];
  u32 cnt = ctl[7]; if (cnt > 8192u) cnt = 8192u;
  u32 T = ctl[4];
  u32 need = (u32)KSEL - cgt;
  bool doEqSort = (cnt > need);  // rare: float-score ties beyond exact fill

  if (doEqSort) {
    u32 nsort = 1; while (nsort < cnt) nsort <<= 1;
    for (u32 idx = t; idx < nsort; idx += 1024) a32[idx] = (idx < cnt) ? bufEq[idx] : 0xFFFFFFFFu;
    __syncthreads();
    for (u32 kk = 2; kk <= nsort; kk <<= 1)
      for (u32 j = kk >> 1; j > 0; j >>= 1) {
        for (u32 idx = t; idx < nsort; idx += 1024) {
          u32 pl = idx ^ j;
          if (pl > idx) {
            bool up = ((idx & kk) == 0);
            u32 A = a32[idx], B = a32[pl];
            if (up ? (A > B) : (A < B)) { a32[idx] = B; a32[pl] = A; }
          }
        }
        __syncthreads();
      }
  }

  // load 4 elements into registers (fill slots >= cgt from eq set)
  u64 e[4];
#pragma unroll
  for (int s = 0; s < 4; ++s) {
    int i = (w << 8) | (s << 6) | l;
    if ((u32)i < cgt) {
      e[s] = bufA[i];
    } else {
      u32 q = (u32)i - cgt;
      u32 src = doEqSort ? a32[q] : bufEq[q];
      e[s] = ((u64)T << 32) | (u32)(~src);
    }
  }
  __syncthreads();  // eq-sort reads done before main sort reuses LDS

  for (int k = 2; k <= KSEL; k <<= 1) {
    // cross-wave phases j >= 256 (wave-uniform direction)
    for (int j = k >> 1; j >= 256; j >>= 1) {
      __syncthreads();
#pragma unroll
      for (int s = 0; s < 4; ++s) a[(w << 8) | (s << 6) | l] = e[s];
      __syncthreads();
      int i0 = (w << 8) | l;
      bool kmax = (((i0 & k) == 0) != ((i0 & j) != 0));
#pragma unroll
      for (int s = 0; s < 4; ++s) {
        u64 p = a[((w << 8) | (s << 6) | l) ^ j];
        e[s] = kmax ? mx64_(e[s], p) : mn64_(e[s], p);
      }
    }
    // j = 128: register pairs (0,2),(1,3); direction uniform across slots
    if (k >= 256) {
      bool up = ((((w << 8) | l) & k) == 0);
      u64 A, B;
      A = e[0]; B = e[2];
      e[0] = up ? mx64_(A, B) : mn64_(A, B);
      e[2] = up ? mn64_(A, B) : mx64_(A, B);
      A = e[1]; B = e[3];
      e[1] = up ? mx64_(A, B) : mn64_(A, B);
      e[3] = up ? mn64_(A, B) : mx64_(A, B);
    }
    // j = 64: register pairs (0,1),(2,3)
    if (k >= 128) {
      bool upA = ((((w << 8) | (0 << 6) | l) & k) == 0);
      bool upB = ((((w << 8) | (2 << 6) | l) & k) == 0);
      u64 A, B;
      A = e[0]; B = e[1];
      e[0] = upA ? mx64_(A, B) : mn64_(A, B);
      e[1] = upA ? mn64_(A, B) : mx64_(A, B);
      A = e[2]; B = e[3];
      e[2] = upB ? mx64_(A, B) : mn64_(A, B);
      e[3] = upB ? mn64_(A, B) : mx64_(A, B);
    }
    // j <= 32: shuffle phases, no barrier
    for (int j = (k >> 1 < 32 ? k >> 1 : 32); j >= 1; j >>= 1) {
#pragma unroll
      for (int s = 0; s < 4; ++s) {
        u64 p = __shfl_xor(e[s], j, 64);
        int i = (w << 8) | (s << 6) | l;
        bool kmax = (((i & k) == 0) != ((l & j) != 0));
        e[s] = kmax ? mx64_(e[s], p) : mn64_(e[s], p);
      }
    }
  }

  // park sorted keys in LDS for the epilogue
  __syncthreads();
#pragma unroll
  for (int s = 0; s < 4; ++s) a[(w << 8) | (s << 6) | l] = e[s];
  __syncthreads();

  for (int idx = t; idx < KSEL; idx += 1024) {
    u64 kv = a[idx];
    u32 oi = ~((u32)kv);
    float sc = __uint_as_float((u32)(kv >> 32));
    sIdx[idx] = oi;
    sScore[idx] = sc;
    if (sc > 0.0f) {
      bool last = (idx == KSEL - 1);
      float nsc = last ? -1.0f : __uint_as_float((u32)(a[idx + 1] >> 32));
      if (last || nsc <= 0.0f) ctl[10] = (u32)(idx + 1);  // valid count V
    }
    const float* row = pred + (size_t)oi * ROWF;
    float x = row[0], y = row[1], wd = row[2], h = row[3];
    float hw = __fmul_rn(wd, 0.5f), hh = __fmul_rn(h, 0.5f);
    float4 b;
    b.x = fsub_rn_(y, hh);   // y1
    b.y = fsub_rn_(x, hw);   // x1
    b.z = __fadd_rn(y, hh);  // y2
    b.w = __fadd_rn(x, hw);  // x2
    boxes[idx] = b;
  }
}

// ---- IoU suppression bit-matrix: wave = 64 columns, ballot = one word ----
__global__ void __launch_bounds__(256) k_iou(const float4* __restrict__ boxes,
                                             u64* __restrict__ mat) {
  int wave = threadIdx.x >> 6, lane = threadIdx.x & 63;
  int cw = blockIdx.x * 4 + wave;     // word (column-block) index 0..63
  int j = (cw << 6) | lane;           // column 0..4095
  int i0 = blockIdx.y * 128;
  float4 bj = boxes[j];
  float areaJ = __fmul_rn(fsub_rn_(bj.z, bj.x), fsub_rn_(bj.w, bj.y));
  for (int i = i0; i < i0 + 128; ++i) {
    float4 bi = boxes[i];
    float areaI = __fmul_rn(fsub_rn_(bi.z, bi.x), fsub_rn_(bi.w, bi.y));
    float iy1 = fmaxf(bi.x, bj.x);
    float ix1 = fmaxf(bi.y, bj.y);
    float iy2 = fminf(bi.z, bj.z);
    float ix2 = fminf(bi.w, bj.w);
    float dy = fmaxf(fsub_rn_(iy2, iy1), 0.0f);
    float dx = fmaxf(fsub_rn_(ix2, ix1), 0.0f);
    float inter = __fmul_rn(dy, dx);
    float uni = fsub_rn_(__fadd_rn(areaI, areaJ), inter);
    float iou = inter / fmaxf(uni, 1e-9f);
    bool p = (j > i) && (iou > IOU_T);
    u64 m = __ballot(p);
    if (lane == 0) mat[(size_t)i * 64 + cw] = m;
  }
}

// ---- greedy NMS scan: 1 wave, lane owns one 64-bit suppressed word.
// 64-deep unconditional register prefetch ring; diagonal word via readlane
// (scalar) instead of a second load stream; early exit at MAXDET kept. ----
#define NMS_D 64
__global__ void __launch_bounds__(64) k_nms(const u64* __restrict__ mat,
                                            u32* __restrict__ ctl,
                                            u32* __restrict__ kept) {
  int lane = threadIdx.x;
  int V = (int)ctl[10];
  u64 rbuf[NMS_D];
#pragma unroll
  for (int d = 0; d < NMS_D; ++d) {
    int pr = (d < V) ? d : 0;
    rbuf[d] = mat[(size_t)pr * 64 + lane];
  }
  u64 removed = 0ull;
  u64 rw = 0ull;
  int kc = 0;
  bool done = (V == 0);
  for (int i0 = 0; i0 < V; i0 += NMS_D) {
    if (done) break;
#pragma unroll
    for (int d = 0; d < NMS_D; ++d) {
      int i = i0 + d;
      u64 rowv = rbuf[d];
      // unconditional prefetch of row i+NMS_D (clamped; dead value past V)
      int nr = i + NMS_D;
      int pr = (nr < V) ? nr : 0;
      rbuf[d] = mat[(size_t)pr * 64 + lane];
      if (!done && i < V) {
        int w = i >> 6;
        if ((i & 63) == 0) rw = readlane64_(removed, w);
        if (((rw >> (i & 63)) & 1ull) == 0ull) {
          if (lane == 0) kept[kc] = (u32)i;
          removed |= rowv;
          rw |= readlane64_(rowv, w);
          ++kc;
          if (kc == MAXDET) done = true;
        }
      }
    }
  }
  if (lane == 0) ctl[8] = (u32)kc;
}

// ---- output: wave per detection slot ----
__global__ void __launch_bounds__(256) k_out(const float* __restrict__ pred,
                                             const u32* __restrict__ ctl,
                                             const u32* __restrict__ kept,
                                             const u32* __restrict__ sIdx,
                                             const float* __restrict__ sScore,
                                             const float4* __restrict__ boxes,
                                             float* __restrict__ out) {
  int wave = threadIdx.x >> 6, lane = threadIdx.x & 63;
  int s = blockIdx.x * 4 + wave;
  if (s >= MAXDET) return;
  int kc = (int)ctl[8];
  if (s < kc) {
    int pos = (int)kept[s];
    u32 oi = sIdx[pos];
    const float* row = pred + (size_t)oi * ROWF;
    float obj = row[4];
    float v = __fmul_rn(row[5 + lane], obj);
    int ci = lane;
    if (lane < 16) {
      float v2 = __fmul_rn(row[69 + lane], obj);
      if (v2 > v) { v = v2; ci = 64 + lane; }
    }
#pragma unroll
    for (int off = 32; off >= 1; off >>= 1) {
      float ov = __shfl_xor(v, off);
      int oc = __shfl_xor(ci, off);
      if (ov > v || (ov == v && oc < ci)) { v = ov; ci = oc; }
    }
    if (lane == 0) {
      ((float4*)out)[s] = boxes[pos];
      out[1200 + s] = (float)ci;
      out[1500 + s] = sScore[pos];
    }
    if (lane < 32) out[1800 + s * 32 + lane] = row[85 + lane];
  } else {
    if (lane == 0) {
      float4 z = {0.f, 0.f, 0.f, 0.f};
      ((float4*)out)[s] = z;
      out[1200 + s] = 0.f;
      out[1500 + s] = 0.f;
    }
    if (lane < 32) out[1800 + s * 32 + lane] = 0.f;
  }
}

extern "C" void kernel_launch(void* const* d_in, const int* in_sizes, int n_in,
                              void* d_out, int out_size, void* d_ws, size_t ws_size,
                              hipStream_t stream) {
  (void)in_sizes; (void)n_in; (void)out_size;
  if (ws_size < WS_NEEDED) return;  // workspace too small — fail visibly
  const float* pred = (const float*)d_in[0];
  float* out = (float*)d_out;
  char* ws = (char*)d_ws;

  u32* hist1 = (u32*)(ws + HIST1_OFF);
  u32* hist2 = (u32*)(ws + HIST2_OFF);
  u32* hist3 = (u32*)(ws + HIST3_OFF);
  u32* ctl = (u32*)(ws + CTL_OFF);
  float* score = (float*)(ws + SCORE_OFF);
  u64* bufA = (u64*)(ws + BUFA_OFF);
  u32* bufEq = (u32*)(ws + BUFEQ_OFF);
  u32* sIdx = (u32*)(ws + SIDX_OFF);
  float* sScore = (float*)(ws + SSC_OFF);
  float4* boxes = (float4*)(ws + BOXES_OFF);
  u32* kept = (u32*)(ws + KEPT_OFF);
  u64* mat = (u64*)(ws + MAT_OFF);

  hipMemsetAsync(ws, 0, ZERO_BYTES, stream);

  k_score<<<N_ANCH / 64, 256, 0, stream>>>(pred, score, hist1);
  k_scan<<<1, 256, 0, stream>>>(hist1, ctl, 2048, 0);
  int nblk = (N_ANCH + 255) / 256;
  k_hist<<<nblk, 256, 0, stream>>>(score, ctl, hist2, 1);
  k_scan<<<1, 256, 0, stream>>>(hist2, ctl, 2048, 1);
  k_hist<<<nblk, 256, 0, stream>>>(score, ctl, hist3, 2);
  k_scan<<<1, 256, 0, stream>>>(hist3, ctl, 1024, 2);
  k_collect<<<nblk, 256, 0, stream>>>(score, ctl, bufA, bufEq);
  k_sort<<<1, 1024, 0, stream>>>(bufA, bufEq, pred, sIdx, sScore, boxes, ctl);
  k_iou<<<dim3(16, 32), 256, 0, stream>>>(boxes, mat);
  k_nms<<<1, 64, 0, stream>>>(mat, ctl, kept);
  k_out<<<(MAXDET + 3) / 4, 256, 0, stream>>>(pred, ctl, kept, sIdx, sScore, boxes, out);
}